// Round 1
// baseline (279.576 us; speedup 1.0000x reference)
//
#include <hip/hip_runtime.h>

#define DEPTH 128

// Kernel 1: segment boundary search. batch is sorted; start[g] = first index
// with batch[i] >= g, for g in [0, G]. count[g] = start[g+1]-start[g].
__global__ void find_starts_kernel(const int* __restrict__ batch,
                                   int* __restrict__ start, int N, int G) {
    int g = blockIdx.x * blockDim.x + threadIdx.x;
    if (g > G) return;
    int lo = 0, hi = N;
    while (lo < hi) {
        int mid = (lo + hi) >> 1;
        if (batch[mid] < g) lo = mid + 1; else hi = mid;
    }
    start[g] = lo;
}

// Kernel 2: one block per graph. Pool (sum/mean/max) the graph's contiguous
// row range with coalesced float4 loads, then run the 2-layer MLP in-block.
__global__ __launch_bounds__(256) void pool_mlp_kernel(
    const float4* __restrict__ x4, const int* __restrict__ start,
    const float* __restrict__ W1, const float* __restrict__ b1,
    const float* __restrict__ W2, const float* __restrict__ b2,
    float* __restrict__ out, int G)
{
    const int g   = blockIdx.x;
    const int tid = threadIdx.x;
    const int rg  = tid >> 5;   // row group 0..7
    const int d4  = tid & 31;   // float4 column 0..31 (dim = 4*d4)

    const int s0 = start[g];
    const int s1 = start[g + 1];

    float4 sum = make_float4(0.f, 0.f, 0.f, 0.f);
    float4 mx  = make_float4(-INFINITY, -INFINITY, -INFINITY, -INFINITY);

    for (int r = s0 + rg; r < s1; r += 8) {
        float4 v = x4[(size_t)r * 32 + d4];
        sum.x += v.x; sum.y += v.y; sum.z += v.z; sum.w += v.w;
        mx.x = fmaxf(mx.x, v.x); mx.y = fmaxf(mx.y, v.y);
        mx.z = fmaxf(mx.z, v.z); mx.w = fmaxf(mx.w, v.w);
    }

    __shared__ float4 redS[8][32];
    __shared__ float4 redM[8][32];
    redS[rg][d4] = sum;
    redM[rg][d4] = mx;
    __syncthreads();

    __shared__ float hbuf[3 * DEPTH];  // [max | mean | sum]
    __shared__ float abuf[DEPTH];

    if (tid < 32) {
        float4 s = redS[0][d4];
        float4 m = redM[0][d4];
        #pragma unroll
        for (int i = 1; i < 8; ++i) {
            float4 ts = redS[i][d4];
            s.x += ts.x; s.y += ts.y; s.z += ts.z; s.w += ts.w;
            float4 tm = redM[i][d4];
            m.x = fmaxf(m.x, tm.x); m.y = fmaxf(m.y, tm.y);
            m.z = fmaxf(m.z, tm.z); m.w = fmaxf(m.w, tm.w);
        }
        const int cnt = s1 - s0;
        const float inv = 1.0f / (float)(cnt > 1 ? cnt : 1);
        if (cnt == 0) m = make_float4(0.f, 0.f, 0.f, 0.f);
        const int d = d4 * 4;
        hbuf[d + 0] = m.x; hbuf[d + 1] = m.y; hbuf[d + 2] = m.z; hbuf[d + 3] = m.w;
        hbuf[DEPTH + d + 0] = s.x * inv; hbuf[DEPTH + d + 1] = s.y * inv;
        hbuf[DEPTH + d + 2] = s.z * inv; hbuf[DEPTH + d + 3] = s.w * inv;
        hbuf[2 * DEPTH + d + 0] = s.x; hbuf[2 * DEPTH + d + 1] = s.y;
        hbuf[2 * DEPTH + d + 2] = s.z; hbuf[2 * DEPTH + d + 3] = s.w;
    }
    __syncthreads();

    // Layer 1: y1[j] = leaky_relu(b1[j] + sum_k h[k] * W1[j][k]), W1 is [128][384]
    if (tid < DEPTH) {
        float acc = b1[tid];
        const float4* w  = reinterpret_cast<const float4*>(W1 + (size_t)tid * 3 * DEPTH);
        const float4* h4 = reinterpret_cast<const float4*>(hbuf);
        #pragma unroll 8
        for (int k = 0; k < (3 * DEPTH) / 4; ++k) {
            float4 wv = w[k], hv = h4[k];
            acc += wv.x * hv.x + wv.y * hv.y + wv.z * hv.z + wv.w * hv.w;
        }
        abuf[tid] = (acc > 0.f) ? acc : 0.01f * acc;
    }
    __syncthreads();

    // Layer 2: out[j] = b2[j] + sum_i a[i] * W2[j][i], W2 is [128][128]
    if (tid < DEPTH) {
        float acc = b2[tid];
        const float4* w  = reinterpret_cast<const float4*>(W2 + (size_t)tid * DEPTH);
        const float4* a4 = reinterpret_cast<const float4*>(abuf);
        #pragma unroll 8
        for (int k = 0; k < DEPTH / 4; ++k) {
            float4 wv = w[k], av = a4[k];
            acc += wv.x * av.x + wv.y * av.y + wv.z * av.z + wv.w * av.w;
        }
        out[(size_t)g * DEPTH + tid] = acc;
    }
}

extern "C" void kernel_launch(void* const* d_in, const int* in_sizes, int n_in,
                              void* d_out, int out_size, void* d_ws, size_t ws_size,
                              hipStream_t stream) {
    const float* x     = (const float*)d_in[0];
    const int*   batch = (const int*)d_in[1];
    // d_in[2] is the scalar output_dim (device side); derive G host-side instead.
    const float* W1 = (const float*)d_in[3];
    const float* b1 = (const float*)d_in[4];
    const float* W2 = (const float*)d_in[5];
    const float* b2 = (const float*)d_in[6];
    float* out = (float*)d_out;

    const int N = in_sizes[0] / DEPTH;   // 2,000,000 nodes
    const int G = out_size / DEPTH;      // 4096 graphs

    int* start = (int*)d_ws;             // G+1 ints, rewritten fully every call

    find_starts_kernel<<<(G + 256) / 256, 256, 0, stream>>>(batch, start, N, G);
    pool_mlp_kernel<<<G, 256, 0, stream>>>(
        (const float4*)x, start, W1, b1, W2, b2, out, G);
}

// Round 2
// 251.717 us; speedup vs baseline: 1.1107x; 1.1107x over previous
//
#include <hip/hip_runtime.h>

#define DEPTH 128

// Kernel 1: segment boundary search. batch is sorted; start[g] = first index
// with batch[i] >= g, for g in [0, G].
__global__ void find_starts_kernel(const int* __restrict__ batch,
                                   int* __restrict__ start, int N, int G) {
    int g = blockIdx.x * blockDim.x + threadIdx.x;
    if (g > G) return;
    int lo = 0, hi = N;
    while (lo < hi) {
        int mid = (lo + hi) >> 1;
        if (batch[mid] < g) lo = mid + 1; else hi = mid;
    }
    start[g] = lo;
}

// Kernel 2: one block per graph. Pool (sum/mean/max) the graph's contiguous
// row range with coalesced float4 loads (4x unrolled, 4 independent
// accumulator sets for memory-level parallelism), then the 2-layer MLP.
__global__ __launch_bounds__(256) void pool_mlp_kernel(
    const float4* __restrict__ x4, const int* __restrict__ start,
    const float* __restrict__ W1, const float* __restrict__ b1,
    const float* __restrict__ W2, const float* __restrict__ b2,
    float* __restrict__ out, int G)
{
    const int g   = blockIdx.x;
    const int tid = threadIdx.x;
    const int rg  = tid >> 5;   // row group 0..7
    const int d4  = tid & 31;   // float4 column 0..31 (dim = 4*d4)

    const int s0 = start[g];
    const int s1 = start[g + 1];

    float4 sum0 = make_float4(0.f, 0.f, 0.f, 0.f);
    float4 sum1 = sum0, sum2 = sum0, sum3 = sum0;
    float4 mx0 = make_float4(-INFINITY, -INFINITY, -INFINITY, -INFINITY);
    float4 mx1 = mx0, mx2 = mx0, mx3 = mx0;

    int r = s0 + rg;
    // Main loop: 4 rows (stride 8) per iteration -> 4 loads in flight/wave.
    for (; r + 24 < s1; r += 32) {
        float4 v0 = x4[(size_t)(r)      * 32 + d4];
        float4 v1 = x4[(size_t)(r + 8)  * 32 + d4];
        float4 v2 = x4[(size_t)(r + 16) * 32 + d4];
        float4 v3 = x4[(size_t)(r + 24) * 32 + d4];
        sum0.x += v0.x; sum0.y += v0.y; sum0.z += v0.z; sum0.w += v0.w;
        mx0.x = fmaxf(mx0.x, v0.x); mx0.y = fmaxf(mx0.y, v0.y);
        mx0.z = fmaxf(mx0.z, v0.z); mx0.w = fmaxf(mx0.w, v0.w);
        sum1.x += v1.x; sum1.y += v1.y; sum1.z += v1.z; sum1.w += v1.w;
        mx1.x = fmaxf(mx1.x, v1.x); mx1.y = fmaxf(mx1.y, v1.y);
        mx1.z = fmaxf(mx1.z, v1.z); mx1.w = fmaxf(mx1.w, v1.w);
        sum2.x += v2.x; sum2.y += v2.y; sum2.z += v2.z; sum2.w += v2.w;
        mx2.x = fmaxf(mx2.x, v2.x); mx2.y = fmaxf(mx2.y, v2.y);
        mx2.z = fmaxf(mx2.z, v2.z); mx2.w = fmaxf(mx2.w, v2.w);
        sum3.x += v3.x; sum3.y += v3.y; sum3.z += v3.z; sum3.w += v3.w;
        mx3.x = fmaxf(mx3.x, v3.x); mx3.y = fmaxf(mx3.y, v3.y);
        mx3.z = fmaxf(mx3.z, v3.z); mx3.w = fmaxf(mx3.w, v3.w);
    }
    // Tail: remaining rows one at a time.
    for (; r < s1; r += 8) {
        float4 v = x4[(size_t)r * 32 + d4];
        sum0.x += v.x; sum0.y += v.y; sum0.z += v.z; sum0.w += v.w;
        mx0.x = fmaxf(mx0.x, v.x); mx0.y = fmaxf(mx0.y, v.y);
        mx0.z = fmaxf(mx0.z, v.z); mx0.w = fmaxf(mx0.w, v.w);
    }

    // Fold the 4 accumulator sets.
    float4 sum = make_float4(sum0.x + sum1.x + sum2.x + sum3.x,
                             sum0.y + sum1.y + sum2.y + sum3.y,
                             sum0.z + sum1.z + sum2.z + sum3.z,
                             sum0.w + sum1.w + sum2.w + sum3.w);
    float4 mx = make_float4(fmaxf(fmaxf(mx0.x, mx1.x), fmaxf(mx2.x, mx3.x)),
                            fmaxf(fmaxf(mx0.y, mx1.y), fmaxf(mx2.y, mx3.y)),
                            fmaxf(fmaxf(mx0.z, mx1.z), fmaxf(mx2.z, mx3.z)),
                            fmaxf(fmaxf(mx0.w, mx1.w), fmaxf(mx2.w, mx3.w)));

    __shared__ float4 redS[8][32];
    __shared__ float4 redM[8][32];
    redS[rg][d4] = sum;
    redM[rg][d4] = mx;
    __syncthreads();

    __shared__ float hbuf[3 * DEPTH];  // [max | mean | sum]
    __shared__ float abuf[DEPTH];

    if (tid < 32) {
        float4 s = redS[0][d4];
        float4 m = redM[0][d4];
        #pragma unroll
        for (int i = 1; i < 8; ++i) {
            float4 ts = redS[i][d4];
            s.x += ts.x; s.y += ts.y; s.z += ts.z; s.w += ts.w;
            float4 tm = redM[i][d4];
            m.x = fmaxf(m.x, tm.x); m.y = fmaxf(m.y, tm.y);
            m.z = fmaxf(m.z, tm.z); m.w = fmaxf(m.w, tm.w);
        }
        const int cnt = s1 - s0;
        const float inv = 1.0f / (float)(cnt > 1 ? cnt : 1);
        if (cnt == 0) m = make_float4(0.f, 0.f, 0.f, 0.f);
        const int d = d4 * 4;
        hbuf[d + 0] = m.x; hbuf[d + 1] = m.y; hbuf[d + 2] = m.z; hbuf[d + 3] = m.w;
        hbuf[DEPTH + d + 0] = s.x * inv; hbuf[DEPTH + d + 1] = s.y * inv;
        hbuf[DEPTH + d + 2] = s.z * inv; hbuf[DEPTH + d + 3] = s.w * inv;
        hbuf[2 * DEPTH + d + 0] = s.x; hbuf[2 * DEPTH + d + 1] = s.y;
        hbuf[2 * DEPTH + d + 2] = s.z; hbuf[2 * DEPTH + d + 3] = s.w;
    }
    __syncthreads();

    // Layer 1: y1[j] = leaky_relu(b1[j] + sum_k h[k] * W1[j][k]), W1 is [128][384]
    if (tid < DEPTH) {
        float acc = b1[tid];
        const float4* w  = reinterpret_cast<const float4*>(W1 + (size_t)tid * 3 * DEPTH);
        const float4* h4 = reinterpret_cast<const float4*>(hbuf);
        #pragma unroll 8
        for (int k = 0; k < (3 * DEPTH) / 4; ++k) {
            float4 wv = w[k], hv = h4[k];
            acc += wv.x * hv.x + wv.y * hv.y + wv.z * hv.z + wv.w * hv.w;
        }
        abuf[tid] = (acc > 0.f) ? acc : 0.01f * acc;
    }
    __syncthreads();

    // Layer 2: out[j] = b2[j] + sum_i a[i] * W2[j][i], W2 is [128][128]
    if (tid < DEPTH) {
        float acc = b2[tid];
        const float4* w  = reinterpret_cast<const float4*>(W2 + (size_t)tid * DEPTH);
        const float4* a4 = reinterpret_cast<const float4*>(abuf);
        #pragma unroll 8
        for (int k = 0; k < DEPTH / 4; ++k) {
            float4 wv = w[k], av = a4[k];
            acc += wv.x * av.x + wv.y * av.y + wv.z * av.z + wv.w * av.w;
        }
        out[(size_t)g * DEPTH + tid] = acc;
    }
}

extern "C" void kernel_launch(void* const* d_in, const int* in_sizes, int n_in,
                              void* d_out, int out_size, void* d_ws, size_t ws_size,
                              hipStream_t stream) {
    const float* x     = (const float*)d_in[0];
    const int*   batch = (const int*)d_in[1];
    const float* W1 = (const float*)d_in[3];
    const float* b1 = (const float*)d_in[4];
    const float* W2 = (const float*)d_in[5];
    const float* b2 = (const float*)d_in[6];
    float* out = (float*)d_out;

    const int N = in_sizes[0] / DEPTH;   // 2,000,000 nodes
    const int G = out_size / DEPTH;      // 4096 graphs

    int* start = (int*)d_ws;             // G+1 ints, rewritten fully every call

    find_starts_kernel<<<(G + 256) / 256, 256, 0, stream>>>(batch, start, N, G);
    pool_mlp_kernel<<<G, 256, 0, stream>>>(
        (const float4*)x, start, W1, b1, W2, b2, out, G);
}